// Round 3
// baseline (962.362 us; speedup 1.0000x reference)
//
#include <hip/hip_runtime.h>
#include <cstdint>

// CamPoseNet: bit-faithful JAX threefry replication (validated rounds 1-2).
// Round 3: dynamic work-queue compaction.
//  - subkey chain precomputed by pre-kernel into d_ws (5 threefrys/draw not 8)
//  - each lane owns ONE row at a time; on accept it stores and grabs the next
//    row from a device-scope atomic counter (wave-aggregated by HW) -> perfect
//    load balance, draws/row ~= mean (4.2) instead of wave-max (~15).
//  - latency scheduling: Z/q loads issued at row-grab, first USED ~700 cycles
//    later (sgi/sig computed after the erfinvs - bit-identical reorder);
//    chain[t] LDS read issued at loop bottom for the next iteration.
// All float ops on the accept-decision path use __f*_rn intrinsics (no FMA
// contraction) - matches XLA:CPU strict mul/add. Do not alter any arithmetic.

#define DEVI __device__ __forceinline__
#define MAXT 96

DEVI uint32_t rotl32(uint32_t v, int s) { return (v << s) | (v >> (32 - s)); }

// Threefry-2x32, 20 rounds (jax._src.prng.threefry2x32).
DEVI void tf2x32(uint32_t k0, uint32_t k1, uint32_t x0, uint32_t x1,
                 uint32_t& o0, uint32_t& o1) {
  const uint32_t kx = k0 ^ k1 ^ 0x1BD11BDAu;
  x0 += k0; x1 += k1;
#define TFR(r) x0 += x1; x1 = rotl32(x1, (r)); x1 ^= x0;
  TFR(13) TFR(15) TFR(26) TFR(6)
  x0 += k1; x1 += kx + 1u;
  TFR(17) TFR(29) TFR(16) TFR(24)
  x0 += kx; x1 += k0 + 2u;
  TFR(13) TFR(15) TFR(26) TFR(6)
  x0 += k0; x1 += k1 + 3u;
  TFR(17) TFR(29) TFR(16) TFR(24)
  x0 += k1; x1 += kx + 4u;
  TFR(13) TFR(15) TFR(26) TFR(6)
  x0 += kx; x1 += k0 + 5u;
#undef TFR
  o0 = x0; o1 = x1;
}

// XLA:CPU Cephes-style f32 log, strict mul/add. x > 0, normal.
DEVI float xla_logf_pos(float xf) {
  uint32_t bits = __float_as_uint(xf);
  float e = (float)((int)(bits >> 23) - 126);
  float m = __uint_as_float((bits & 0x007fffffu) | 0x3f000000u);  // [0.5,1)
  if (m < 0.70710678118654752440f) {
    e = __fsub_rn(e, 1.0f);
    m = __fadd_rn(__fsub_rn(m, 1.0f), m);
  } else {
    m = __fsub_rn(m, 1.0f);
  }
  float z = __fmul_rn(m, m);
  float y = 7.0376836292e-2f;
  y = __fadd_rn(__fmul_rn(y, m), -1.1514610310e-1f);
  y = __fadd_rn(__fmul_rn(y, m),  1.1676998740e-1f);
  y = __fadd_rn(__fmul_rn(y, m), -1.2420140846e-1f);
  y = __fadd_rn(__fmul_rn(y, m),  1.4249322787e-1f);
  y = __fadd_rn(__fmul_rn(y, m), -1.6668057665e-1f);
  y = __fadd_rn(__fmul_rn(y, m),  2.0000714765e-1f);
  y = __fadd_rn(__fmul_rn(y, m), -2.4999993993e-1f);
  y = __fadd_rn(__fmul_rn(y, m),  3.3333331174e-1f);
  y = __fmul_rn(y, m);
  y = __fmul_rn(y, z);
  y = __fadd_rn(y, __fmul_rn(e, -2.12194440e-4f));
  y = __fsub_rn(y, __fmul_rn(z, 0.5f));
  float r = __fadd_rn(m, y);
  r = __fadd_rn(r, __fmul_rn(e, 0.693359375f));
  return r;
}

DEVI float xla_log1pf(float v) {
  if (fabsf(v) < 1e-4f) {
    return __fmul_rn(__fadd_rn(__fmul_rn(-0.5f, v), 1.0f), v);
  }
  return xla_logf_pos(__fadd_rn(v, 1.0f));
}

DEVI float xla_erfinvf(float x) {
  float w = -xla_log1pf(-__fmul_rn(x, x));
  float p;
  if (w < 5.0f) {
    float q = __fsub_rn(w, 2.5f);
    p = 2.81022636e-08f;
    p = __fadd_rn(__fmul_rn(p, q),  3.43273939e-07f);
    p = __fadd_rn(__fmul_rn(p, q), -3.5233877e-06f);
    p = __fadd_rn(__fmul_rn(p, q), -4.39150654e-06f);
    p = __fadd_rn(__fmul_rn(p, q),  0.00021858087f);
    p = __fadd_rn(__fmul_rn(p, q), -0.00125372503f);
    p = __fadd_rn(__fmul_rn(p, q), -0.00417768164f);
    p = __fadd_rn(__fmul_rn(p, q),  0.246640727f);
    p = __fadd_rn(__fmul_rn(p, q),  1.50140941f);
  } else {
    float q = __fsub_rn(sqrtf(w), 3.0f);
    p = -0.000200214257f;
    p = __fadd_rn(__fmul_rn(p, q),  0.000100950558f);
    p = __fadd_rn(__fmul_rn(p, q),  0.00134934322f);
    p = __fadd_rn(__fmul_rn(p, q), -0.00367342844f);
    p = __fadd_rn(__fmul_rn(p, q),  0.00573950773f);
    p = __fadd_rn(__fmul_rn(p, q), -0.0076224613f);
    p = __fadd_rn(__fmul_rn(p, q),  0.00943887047f);
    p = __fadd_rn(__fmul_rn(p, q),  1.00167406f);
    p = __fadd_rn(__fmul_rn(p, q),  2.83297682f);
  }
  return __fmul_rn(p, x);
}

DEVI float u01_from_bits(uint32_t bits) {
  return __fsub_rn(__uint_as_float(0x3f800000u | (bits >> 9)), 1.0f);
}

// ---------------------------------------------------------------------------
// Pre-kernel: compute the split() subkey chain once + init work-queue counter.
// chain[t] = {s1a, s1b, s2a, s2b} at while-iteration t.
__global__ void chain_kernel(const int* __restrict__ seedp,
                             uint4* __restrict__ chain,
                             uint32_t* __restrict__ ctr, int total) {
  if (threadIdx.x == 0) ctr[0] = (uint32_t)total;
  int lane = threadIdx.x;
  if (lane >= 3) return;
  uint32_t ka = 0u, kb = (uint32_t)seedp[0];
  uint32_t x1i = (lane == 2) ? 0u : (uint32_t)(lane + 1);
  for (int t = 0; t < MAXT; ++t) {
    uint32_t o0, o1;
    tf2x32(ka, kb, 0u, x1i, o0, o1);
    uint32_t p0 = __shfl(o0, 1, 64);
    uint32_t p1 = __shfl(o1, 1, 64);
    if (lane == 0) chain[t] = make_uint4(o0, o1, p0, p1);
    ka = __shfl(o0, 2, 64);
    kb = __shfl(o1, 2, 64);
  }
}

// ---------------------------------------------------------------------------
__global__ __launch_bounds__(256) void campose_kernel(
    const float* __restrict__ q, const float* __restrict__ Z,
    float* __restrict__ out, const uint4* __restrict__ chain_g,
    uint32_t* __restrict__ ctr, int N) {
  __shared__ uint4 chain[MAXT];
  for (int i = threadIdx.x; i < MAXT; i += 256) chain[i] = chain_g[i];
  __syncthreads();

  const float sgi0 = __fadd_rn(1.0f, __fmul_rn(2.0f, 1e-6f));
  const float sig0 = sqrtf(__fdiv_rn(1.0f, sgi0));

  int r = blockIdx.x * 256 + threadIdx.x;
  bool have = (r < N);
  int t = 0;
  float Z0 = 0, Z1 = 0, Z2 = 0;
  float qa = 0, qb = 0, qc = 0, qd = 0;
  if (have) {
    Z0 = Z[r * 3 + 0]; Z1 = Z[r * 3 + 1]; Z2 = Z[r * 3 + 2];
    float4 qv = *reinterpret_cast<const float4*>(q + (size_t)r * 4);
    qa = qv.x; qb = qv.y; qc = qv.z; qd = qv.w;
  }
  uint4 ck = chain[0];

  while (__ballot(have)) {
    if (have) {
      const uint32_t base = ((uint32_t)r) * 4u;

      // 4 normal variates (key = s1 subkey, counters base..base+3).
      // sig multiply deferred until after erfinv so the Z load (issued at
      // row-grab) has ~700 cycles of slack before its first use.
      float nv[4];
#pragma unroll
      for (int j = 0; j < 4; ++j) {
        uint32_t o0, o1;
        tf2x32(ck.x, ck.y, 0u, base + (uint32_t)j, o0, o1);
        float u = u01_from_bits(o0 ^ o1);
        float xin = __fadd_rn(__fmul_rn(u, 2.0f), -0.99999994f);
        xin = fmaxf(-0.99999994f, xin);
        nv[j] = __fmul_rn(1.41421356237309504880f, xla_erfinvf(xin));
      }

      // uniform draw (key = s2 subkey, counter r) - independent, issue early
      uint32_t uo0, uo1;
      tf2x32(ck.z, ck.w, 0u, (uint32_t)r, uo0, uo1);
      float uu = u01_from_bits(uo0 ^ uo1);

      // row-dependent constants - first use of Z (bit-identical to before)
      float lam1 = -Z0, lam2 = -Z1, lam3 = -Z2;
      float sgi1 = __fadd_rn(1.0f, __fmul_rn(2.0f, lam1));
      float sgi2 = __fadd_rn(1.0f, __fmul_rn(2.0f, lam2));
      float sgi3 = __fadd_rn(1.0f, __fmul_rn(2.0f, lam3));
      float sig1 = sqrtf(__fdiv_rn(1.0f, sgi1));
      float sig2 = sqrtf(__fdiv_rn(1.0f, sgi2));
      float sig3 = sqrtf(__fdiv_rn(1.0f, sgi3));

      float y0 = __fmul_rn(nv[0], sig0);
      float y1 = __fmul_rn(nv[1], sig1);
      float y2v = __fmul_rn(nv[2], sig2);
      float y3 = __fmul_rn(nv[3], sig3);

      // normalize (sequential reduce order)
      float n2 = __fmul_rn(y0, y0);
      n2 = __fadd_rn(n2, __fmul_rn(y1, y1));
      n2 = __fadd_rn(n2, __fmul_rn(y2v, y2v));
      n2 = __fadd_rn(n2, __fmul_rn(y3, y3));
      float nr = sqrtf(n2);
      y0 = __fdiv_rn(y0, nr); y1 = __fdiv_rn(y1, nr);
      y2v = __fdiv_rn(y2v, nr); y3 = __fdiv_rn(y3, nr);

      float s0q = __fmul_rn(y0, y0), s1q = __fmul_rn(y1, y1);
      float s2q = __fmul_rn(y2v, y2v), s3q = __fmul_rn(y3, y3);

      float s1 = __fmul_rn(s0q, 1e-6f);
      s1 = __fadd_rn(s1, __fmul_rn(s1q, lam1));
      s1 = __fadd_rn(s1, __fmul_rn(s2q, lam2));
      s1 = __fadd_rn(s1, __fmul_rn(s3q, lam3));

      float s2 = __fmul_rn(s0q, sgi0);
      s2 = __fadd_rn(s2, __fmul_rn(s1q, sgi1));
      s2 = __fadd_rn(s2, __fmul_rn(s2q, sgi2));
      s2 = __fadd_rn(s2, __fmul_rn(s3q, sgi3));

      float lr = __fsub_rn(-s1, 2.7725887298583984f);  // 2*f32(ln 4)
      lr = __fadd_rn(lr, 1.5f);
      lr = __fadd_rn(lr, __fmul_rn(2.0f, xla_logf_pos(s2)));

      float lu = (uu > 0.0f) ? xla_logf_pos(uu) : -__builtin_inff();

      ++t;
      if ((lu < lr) || (t >= MAXT)) {
        // epilogue: qn = q/||q||, out = E^T y   (q prefetched at row-grab)
        float a = qa, b = qb, c = qc, d = qd;
        float qn2 = __fmul_rn(a, a);
        qn2 = __fadd_rn(qn2, __fmul_rn(b, b));
        qn2 = __fadd_rn(qn2, __fmul_rn(c, c));
        qn2 = __fadd_rn(qn2, __fmul_rn(d, d));
        float qnr = sqrtf(qn2);
        a = __fdiv_rn(a, qnr); b = __fdiv_rn(b, qnr);
        c = __fdiv_rn(c, qnr); d = __fdiv_rn(d, qnr);

        float o0v = __fadd_rn(__fadd_rn(__fadd_rn(__fmul_rn(a, y0), __fmul_rn(b, y1)),
                                        __fmul_rn(c, y2v)), __fmul_rn(d, y3));
        float o1v = __fadd_rn(__fadd_rn(__fadd_rn(__fmul_rn(-b, y0), __fmul_rn(a, y1)),
                                        __fmul_rn(-d, y2v)), __fmul_rn(c, y3));
        float o2v = __fadd_rn(__fadd_rn(__fadd_rn(__fmul_rn(-c, y0), __fmul_rn(d, y1)),
                                        __fmul_rn(a, y2v)), __fmul_rn(-b, y3));
        float o3v = __fadd_rn(__fadd_rn(__fadd_rn(__fmul_rn(d, y0), __fmul_rn(c, y1)),
                                        __fmul_rn(-b, y2v)), __fmul_rn(-a, y3));
        *reinterpret_cast<float4*>(out + (size_t)r * 4) =
            make_float4(o0v, o1v, o2v, o3v);

        // grab next row from the queue (wave-aggregated atomic)
        r = (int)atomicAdd(ctr, 1u);
        t = 0;
        have = (r < N);
        if (have) {
          Z0 = Z[r * 3 + 0]; Z1 = Z[r * 3 + 1]; Z2 = Z[r * 3 + 2];
          float4 qv = *reinterpret_cast<const float4*>(q + (size_t)r * 4);
          qa = qv.x; qb = qv.y; qc = qv.z; qd = qv.w;
        }
      }
      // prefetch next iteration's subkeys (ds_read has a full iter of slack)
      ck = chain[t];
    }
  }
}

extern "C" void kernel_launch(void* const* d_in, const int* in_sizes, int n_in,
                              void* d_out, int out_size, void* d_ws, size_t ws_size,
                              hipStream_t stream) {
  const float* q = (const float*)d_in[0];
  const float* Z = (const float*)d_in[1];
  const int* seed = (const int*)d_in[2];
  float* out = (float*)d_out;
  int N = in_sizes[0] / 4;

  uint4* chain = (uint4*)d_ws;
  uint32_t* ctr = (uint32_t*)((char*)d_ws + MAXT * sizeof(uint4));

  const int grid = 2048;               // 8 blocks/CU on 256 CUs
  const int total_static = grid * 256; // rows claimed statically at start

  chain_kernel<<<1, 64, 0, stream>>>(seed, chain, ctr, total_static);
  campose_kernel<<<grid, 256, 0, stream>>>(q, Z, out, chain, ctr, N);
}

// Round 4
// 228.782 us; speedup vs baseline: 4.2065x; 4.2065x over previous
//
#include <hip/hip_runtime.h>
#include <cstdint>

// CamPoseNet: bit-faithful JAX threefry replication (validated rounds 1-3).
// Round 4: block-local LDS work queue.
//  R3's single global atomic counter serialized the whole GPU (WRITE_SIZE
//  +13.5MB of hot-line XCD ping-pong, VALUBusy 13%). Replace with one LDS
//  counter per block over a static contiguous 512-row chunk: compaction
//  benefit (draws/row ~= mean 4.2, not wave-max ~14.5) without any
//  cross-block traffic.
//  - subkey chain precomputed by pre-kernel into d_ws (5 threefrys/draw)
//  - Z/q prefetched at row-grab, first used ~700 cycles later
//  - chain[t] LDS read at loop bottom (full iteration of slack)
// All float ops on the accept-decision path use __f*_rn intrinsics (no FMA
// contraction) - matches XLA:CPU strict mul/add. Do not alter any arithmetic.

#define DEVI __device__ __forceinline__
#define MAXT 96
#define GRID 2048

DEVI uint32_t rotl32(uint32_t v, int s) { return (v << s) | (v >> (32 - s)); }

// Threefry-2x32, 20 rounds (jax._src.prng.threefry2x32).
DEVI void tf2x32(uint32_t k0, uint32_t k1, uint32_t x0, uint32_t x1,
                 uint32_t& o0, uint32_t& o1) {
  const uint32_t kx = k0 ^ k1 ^ 0x1BD11BDAu;
  x0 += k0; x1 += k1;
#define TFR(r) x0 += x1; x1 = rotl32(x1, (r)); x1 ^= x0;
  TFR(13) TFR(15) TFR(26) TFR(6)
  x0 += k1; x1 += kx + 1u;
  TFR(17) TFR(29) TFR(16) TFR(24)
  x0 += kx; x1 += k0 + 2u;
  TFR(13) TFR(15) TFR(26) TFR(6)
  x0 += k0; x1 += k1 + 3u;
  TFR(17) TFR(29) TFR(16) TFR(24)
  x0 += k1; x1 += kx + 4u;
  TFR(13) TFR(15) TFR(26) TFR(6)
  x0 += kx; x1 += k0 + 5u;
#undef TFR
  o0 = x0; o1 = x1;
}

// XLA:CPU Cephes-style f32 log, strict mul/add. x > 0, normal.
DEVI float xla_logf_pos(float xf) {
  uint32_t bits = __float_as_uint(xf);
  float e = (float)((int)(bits >> 23) - 126);
  float m = __uint_as_float((bits & 0x007fffffu) | 0x3f000000u);  // [0.5,1)
  if (m < 0.70710678118654752440f) {
    e = __fsub_rn(e, 1.0f);
    m = __fadd_rn(__fsub_rn(m, 1.0f), m);
  } else {
    m = __fsub_rn(m, 1.0f);
  }
  float z = __fmul_rn(m, m);
  float y = 7.0376836292e-2f;
  y = __fadd_rn(__fmul_rn(y, m), -1.1514610310e-1f);
  y = __fadd_rn(__fmul_rn(y, m),  1.1676998740e-1f);
  y = __fadd_rn(__fmul_rn(y, m), -1.2420140846e-1f);
  y = __fadd_rn(__fmul_rn(y, m),  1.4249322787e-1f);
  y = __fadd_rn(__fmul_rn(y, m), -1.6668057665e-1f);
  y = __fadd_rn(__fmul_rn(y, m),  2.0000714765e-1f);
  y = __fadd_rn(__fmul_rn(y, m), -2.4999993993e-1f);
  y = __fadd_rn(__fmul_rn(y, m),  3.3333331174e-1f);
  y = __fmul_rn(y, m);
  y = __fmul_rn(y, z);
  y = __fadd_rn(y, __fmul_rn(e, -2.12194440e-4f));
  y = __fsub_rn(y, __fmul_rn(z, 0.5f));
  float r = __fadd_rn(m, y);
  r = __fadd_rn(r, __fmul_rn(e, 0.693359375f));
  return r;
}

DEVI float xla_log1pf(float v) {
  if (fabsf(v) < 1e-4f) {
    return __fmul_rn(__fadd_rn(__fmul_rn(-0.5f, v), 1.0f), v);
  }
  return xla_logf_pos(__fadd_rn(v, 1.0f));
}

DEVI float xla_erfinvf(float x) {
  float w = -xla_log1pf(-__fmul_rn(x, x));
  float p;
  if (w < 5.0f) {
    float q = __fsub_rn(w, 2.5f);
    p = 2.81022636e-08f;
    p = __fadd_rn(__fmul_rn(p, q),  3.43273939e-07f);
    p = __fadd_rn(__fmul_rn(p, q), -3.5233877e-06f);
    p = __fadd_rn(__fmul_rn(p, q), -4.39150654e-06f);
    p = __fadd_rn(__fmul_rn(p, q),  0.00021858087f);
    p = __fadd_rn(__fmul_rn(p, q), -0.00125372503f);
    p = __fadd_rn(__fmul_rn(p, q), -0.00417768164f);
    p = __fadd_rn(__fmul_rn(p, q),  0.246640727f);
    p = __fadd_rn(__fmul_rn(p, q),  1.50140941f);
  } else {
    float q = __fsub_rn(sqrtf(w), 3.0f);
    p = -0.000200214257f;
    p = __fadd_rn(__fmul_rn(p, q),  0.000100950558f);
    p = __fadd_rn(__fmul_rn(p, q),  0.00134934322f);
    p = __fadd_rn(__fmul_rn(p, q), -0.00367342844f);
    p = __fadd_rn(__fmul_rn(p, q),  0.00573950773f);
    p = __fadd_rn(__fmul_rn(p, q), -0.0076224613f);
    p = __fadd_rn(__fmul_rn(p, q),  0.00943887047f);
    p = __fadd_rn(__fmul_rn(p, q),  1.00167406f);
    p = __fadd_rn(__fmul_rn(p, q),  2.83297682f);
  }
  return __fmul_rn(p, x);
}

DEVI float u01_from_bits(uint32_t bits) {
  return __fsub_rn(__uint_as_float(0x3f800000u | (bits >> 9)), 1.0f);
}

// ---------------------------------------------------------------------------
// Pre-kernel: compute the split() subkey chain once.
// chain[t] = {s1a, s1b, s2a, s2b} at while-iteration t.
__global__ void chain_kernel(const int* __restrict__ seedp,
                             uint4* __restrict__ chain) {
  int lane = threadIdx.x;
  if (lane >= 3) return;
  uint32_t ka = 0u, kb = (uint32_t)seedp[0];
  uint32_t x1i = (lane == 2) ? 0u : (uint32_t)(lane + 1);
  for (int t = 0; t < MAXT; ++t) {
    uint32_t o0, o1;
    tf2x32(ka, kb, 0u, x1i, o0, o1);
    uint32_t p0 = __shfl(o0, 1, 64);
    uint32_t p1 = __shfl(o1, 1, 64);
    if (lane == 0) chain[t] = make_uint4(o0, o1, p0, p1);
    ka = __shfl(o0, 2, 64);
    kb = __shfl(o1, 2, 64);
  }
}

// ---------------------------------------------------------------------------
__global__ __launch_bounds__(256) void campose_kernel(
    const float* __restrict__ q, const float* __restrict__ Z,
    float* __restrict__ out, const uint4* __restrict__ chain_g,
    int N, int C) {
  __shared__ uint4 chain[MAXT];
  __shared__ uint32_t next_row;
  for (int i = threadIdx.x; i < MAXT; i += 256) chain[i] = chain_g[i];
  const int rbeg = blockIdx.x * C;
  const int rend = min(N, rbeg + C);
  if (threadIdx.x == 0) next_row = (uint32_t)(rbeg + 256);
  __syncthreads();

  const float sgi0 = __fadd_rn(1.0f, __fmul_rn(2.0f, 1e-6f));
  const float sig0 = sqrtf(__fdiv_rn(1.0f, sgi0));

  int r = rbeg + threadIdx.x;
  bool have = (r < rend);
  int t = 0;
  float Z0 = 0, Z1 = 0, Z2 = 0;
  float qa = 0, qb = 0, qc = 0, qd = 0;
  if (have) {
    Z0 = Z[r * 3 + 0]; Z1 = Z[r * 3 + 1]; Z2 = Z[r * 3 + 2];
    float4 qv = *reinterpret_cast<const float4*>(q + (size_t)r * 4);
    qa = qv.x; qb = qv.y; qc = qv.z; qd = qv.w;
  }
  uint4 ck = chain[0];

  while (__ballot(have)) {
    if (have) {
      const uint32_t base = ((uint32_t)r) * 4u;

      // 4 normal variates (key = s1 subkey, counters base..base+3).
      // sig multiply deferred until after erfinv so the Z load (issued at
      // row-grab) has ~700 cycles of slack before its first use.
      float nv[4];
#pragma unroll
      for (int j = 0; j < 4; ++j) {
        uint32_t o0, o1;
        tf2x32(ck.x, ck.y, 0u, base + (uint32_t)j, o0, o1);
        float u = u01_from_bits(o0 ^ o1);
        float xin = __fadd_rn(__fmul_rn(u, 2.0f), -0.99999994f);
        xin = fmaxf(-0.99999994f, xin);
        nv[j] = __fmul_rn(1.41421356237309504880f, xla_erfinvf(xin));
      }

      // uniform draw (key = s2 subkey, counter r)
      uint32_t uo0, uo1;
      tf2x32(ck.z, ck.w, 0u, (uint32_t)r, uo0, uo1);
      float uu = u01_from_bits(uo0 ^ uo1);

      // row-dependent constants - first use of Z (bit-identical order)
      float lam1 = -Z0, lam2 = -Z1, lam3 = -Z2;
      float sgi1 = __fadd_rn(1.0f, __fmul_rn(2.0f, lam1));
      float sgi2 = __fadd_rn(1.0f, __fmul_rn(2.0f, lam2));
      float sgi3 = __fadd_rn(1.0f, __fmul_rn(2.0f, lam3));
      float sig1 = sqrtf(__fdiv_rn(1.0f, sgi1));
      float sig2 = sqrtf(__fdiv_rn(1.0f, sgi2));
      float sig3 = sqrtf(__fdiv_rn(1.0f, sgi3));

      float y0 = __fmul_rn(nv[0], sig0);
      float y1 = __fmul_rn(nv[1], sig1);
      float y2v = __fmul_rn(nv[2], sig2);
      float y3 = __fmul_rn(nv[3], sig3);

      // normalize (sequential reduce order)
      float n2 = __fmul_rn(y0, y0);
      n2 = __fadd_rn(n2, __fmul_rn(y1, y1));
      n2 = __fadd_rn(n2, __fmul_rn(y2v, y2v));
      n2 = __fadd_rn(n2, __fmul_rn(y3, y3));
      float nr = sqrtf(n2);
      y0 = __fdiv_rn(y0, nr); y1 = __fdiv_rn(y1, nr);
      y2v = __fdiv_rn(y2v, nr); y3 = __fdiv_rn(y3, nr);

      float s0q = __fmul_rn(y0, y0), s1q = __fmul_rn(y1, y1);
      float s2q = __fmul_rn(y2v, y2v), s3q = __fmul_rn(y3, y3);

      float s1 = __fmul_rn(s0q, 1e-6f);
      s1 = __fadd_rn(s1, __fmul_rn(s1q, lam1));
      s1 = __fadd_rn(s1, __fmul_rn(s2q, lam2));
      s1 = __fadd_rn(s1, __fmul_rn(s3q, lam3));

      float s2 = __fmul_rn(s0q, sgi0);
      s2 = __fadd_rn(s2, __fmul_rn(s1q, sgi1));
      s2 = __fadd_rn(s2, __fmul_rn(s2q, sgi2));
      s2 = __fadd_rn(s2, __fmul_rn(s3q, sgi3));

      float lr = __fsub_rn(-s1, 2.7725887298583984f);  // 2*f32(ln 4)
      lr = __fadd_rn(lr, 1.5f);
      lr = __fadd_rn(lr, __fmul_rn(2.0f, xla_logf_pos(s2)));

      float lu = (uu > 0.0f) ? xla_logf_pos(uu) : -__builtin_inff();

      ++t;
      if ((lu < lr) || (t >= MAXT)) {
        // epilogue: qn = q/||q||, out = E^T y   (q prefetched at row-grab)
        float a = qa, b = qb, c = qc, d = qd;
        float qn2 = __fmul_rn(a, a);
        qn2 = __fadd_rn(qn2, __fmul_rn(b, b));
        qn2 = __fadd_rn(qn2, __fmul_rn(c, c));
        qn2 = __fadd_rn(qn2, __fmul_rn(d, d));
        float qnr = sqrtf(qn2);
        a = __fdiv_rn(a, qnr); b = __fdiv_rn(b, qnr);
        c = __fdiv_rn(c, qnr); d = __fdiv_rn(d, qnr);

        float o0v = __fadd_rn(__fadd_rn(__fadd_rn(__fmul_rn(a, y0), __fmul_rn(b, y1)),
                                        __fmul_rn(c, y2v)), __fmul_rn(d, y3));
        float o1v = __fadd_rn(__fadd_rn(__fadd_rn(__fmul_rn(-b, y0), __fmul_rn(a, y1)),
                                        __fmul_rn(-d, y2v)), __fmul_rn(c, y3));
        float o2v = __fadd_rn(__fadd_rn(__fadd_rn(__fmul_rn(-c, y0), __fmul_rn(d, y1)),
                                        __fmul_rn(a, y2v)), __fmul_rn(-b, y3));
        float o3v = __fadd_rn(__fadd_rn(__fadd_rn(__fmul_rn(d, y0), __fmul_rn(c, y1)),
                                        __fmul_rn(-b, y2v)), __fmul_rn(-a, y3));
        *reinterpret_cast<float4*>(out + (size_t)r * 4) =
            make_float4(o0v, o1v, o2v, o3v);

        // grab next row from the BLOCK-LOCAL queue (LDS atomic, no global
        // contention)
        r = (int)atomicAdd(&next_row, 1u);
        t = 0;
        have = (r < rend);
        if (have) {
          Z0 = Z[r * 3 + 0]; Z1 = Z[r * 3 + 1]; Z2 = Z[r * 3 + 2];
          float4 qv = *reinterpret_cast<const float4*>(q + (size_t)r * 4);
          qa = qv.x; qb = qv.y; qc = qv.z; qd = qv.w;
        }
      }
      // prefetch next iteration's subkeys (ds_read has a full iter of slack)
      ck = chain[t];
    }
  }
}

extern "C" void kernel_launch(void* const* d_in, const int* in_sizes, int n_in,
                              void* d_out, int out_size, void* d_ws, size_t ws_size,
                              hipStream_t stream) {
  const float* q = (const float*)d_in[0];
  const float* Z = (const float*)d_in[1];
  const int* seed = (const int*)d_in[2];
  float* out = (float*)d_out;
  int N = in_sizes[0] / 4;

  uint4* chain = (uint4*)d_ws;
  chain_kernel<<<1, 64, 0, stream>>>(seed, chain);

  int C = (N + GRID - 1) / GRID;  // rows per block (contiguous chunk)
  campose_kernel<<<GRID, 256, 0, stream>>>(q, Z, out, chain, N, C);
}

// Round 5
// 195.317 us; speedup vs baseline: 4.9272x; 1.1713x over previous
//
#include <hip/hip_runtime.h>
#include <cstdint>

// CamPoseNet: bit-faithful JAX threefry replication (validated rounds 1-4).
// Round 5: deep block-local queue + in-kernel chain producer + latency-free
// hot loop.
//  - GRID=512 (C=2048 rows/block, 8 rows/lane): per-wave tail (~12 iters)
//    amortized 4x better than R4's 2 rows/lane (2.3x -> 1.33x inflation).
//  - wave 0 of each block produces the 96-entry split()-chain into LDS behind
//    an LDS watermark; waves 1-3 consume immediately (producer ~5x faster
//    than consumption rate). Eliminates the separate chain kernel (~30us).
//  - hot loop: chain[t+1] prefetched at iteration top; chain[0] cached in
//    registers for accepts; NEXT row+Z pre-grabbed at accept (queue atomic
//    and Z load get ~4.5 iterations of slack); E^T epilogue deferred to a
//    coalesced per-block pass after the loop; select-based erfinv branches.
// All float ops on the accept-decision path use __f*_rn intrinsics (no FMA
// contraction) - matches XLA:CPU strict mul/add. Do not alter any arithmetic.

#define DEVI __device__ __forceinline__
#define MAXT 96
#define GRID 512
#define NT 256

DEVI uint32_t rotl32(uint32_t v, int s) { return (v << s) | (v >> (32 - s)); }

// Threefry-2x32, 20 rounds (jax._src.prng.threefry2x32).
DEVI void tf2x32(uint32_t k0, uint32_t k1, uint32_t x0, uint32_t x1,
                 uint32_t& o0, uint32_t& o1) {
  const uint32_t kx = k0 ^ k1 ^ 0x1BD11BDAu;
  x0 += k0; x1 += k1;
#define TFR(r) x0 += x1; x1 = rotl32(x1, (r)); x1 ^= x0;
  TFR(13) TFR(15) TFR(26) TFR(6)
  x0 += k1; x1 += kx + 1u;
  TFR(17) TFR(29) TFR(16) TFR(24)
  x0 += kx; x1 += k0 + 2u;
  TFR(13) TFR(15) TFR(26) TFR(6)
  x0 += k0; x1 += k1 + 3u;
  TFR(17) TFR(29) TFR(16) TFR(24)
  x0 += k1; x1 += kx + 4u;
  TFR(13) TFR(15) TFR(26) TFR(6)
  x0 += kx; x1 += k0 + 5u;
#undef TFR
  o0 = x0; o1 = x1;
}

// XLA:CPU Cephes-style f32 log, strict mul/add. x > 0, normal.
DEVI float xla_logf_pos(float xf) {
  uint32_t bits = __float_as_uint(xf);
  float e = (float)((int)(bits >> 23) - 126);
  float m = __uint_as_float((bits & 0x007fffffu) | 0x3f000000u);  // [0.5,1)
  if (m < 0.70710678118654752440f) {
    e = __fsub_rn(e, 1.0f);
    m = __fadd_rn(__fsub_rn(m, 1.0f), m);
  } else {
    m = __fsub_rn(m, 1.0f);
  }
  float z = __fmul_rn(m, m);
  float y = 7.0376836292e-2f;
  y = __fadd_rn(__fmul_rn(y, m), -1.1514610310e-1f);
  y = __fadd_rn(__fmul_rn(y, m),  1.1676998740e-1f);
  y = __fadd_rn(__fmul_rn(y, m), -1.2420140846e-1f);
  y = __fadd_rn(__fmul_rn(y, m),  1.4249322787e-1f);
  y = __fadd_rn(__fmul_rn(y, m), -1.6668057665e-1f);
  y = __fadd_rn(__fmul_rn(y, m),  2.0000714765e-1f);
  y = __fadd_rn(__fmul_rn(y, m), -2.4999993993e-1f);
  y = __fadd_rn(__fmul_rn(y, m),  3.3333331174e-1f);
  y = __fmul_rn(y, m);
  y = __fmul_rn(y, z);
  y = __fadd_rn(y, __fmul_rn(e, -2.12194440e-4f));
  y = __fsub_rn(y, __fmul_rn(z, 0.5f));
  float r = __fadd_rn(m, y);
  r = __fadd_rn(r, __fmul_rn(e, 0.693359375f));
  return r;
}

// XLA EmitLog1p, select form (bit-identical per lane to the branchy version)
DEVI float xla_log1pf(float v) {
  float small = __fmul_rn(__fadd_rn(__fmul_rn(-0.5f, v), 1.0f), v);
  float big = xla_logf_pos(__fadd_rn(v, 1.0f));
  return (fabsf(v) < 1e-4f) ? small : big;
}

// XLA ErfInv32, coefficient-select form: identical op sequence per lane as
// the taken branch -> bit-exact, but no dual-path exec-mask waste.
DEVI float xla_erfinvf(float x) {
  float w = -xla_log1pf(-__fmul_rn(x, x));
  bool c = (w < 5.0f);
  float qc = __fsub_rn(w, 2.5f);
  float qr = __fsub_rn(sqrtf(w), 3.0f);
  float q = c ? qc : qr;
  float p =                          c ? 2.81022636e-08f : -0.000200214257f;
  p = __fadd_rn(__fmul_rn(p, q), c ?  3.43273939e-07f :  0.000100950558f);
  p = __fadd_rn(__fmul_rn(p, q), c ? -3.5233877e-06f  :  0.00134934322f);
  p = __fadd_rn(__fmul_rn(p, q), c ? -4.39150654e-06f : -0.00367342844f);
  p = __fadd_rn(__fmul_rn(p, q), c ?  0.00021858087f  :  0.00573950773f);
  p = __fadd_rn(__fmul_rn(p, q), c ? -0.00125372503f  : -0.0076224613f);
  p = __fadd_rn(__fmul_rn(p, q), c ? -0.00417768164f  :  0.00943887047f);
  p = __fadd_rn(__fmul_rn(p, q), c ?  0.246640727f    :  1.00167406f);
  p = __fadd_rn(__fmul_rn(p, q), c ?  1.50140941f     :  2.83297682f);
  return __fmul_rn(p, x);
}

DEVI float u01_from_bits(uint32_t bits) {
  return __fsub_rn(__uint_as_float(0x3f800000u | (bits >> 9)), 1.0f);
}

// ---------------------------------------------------------------------------
__global__ __launch_bounds__(256) void campose_kernel(
    const float* __restrict__ q, const float* __restrict__ Z,
    float* __restrict__ out, const int* __restrict__ seedp, int N, int C) {
  __shared__ uint4 chain[MAXT + 1];
  __shared__ uint32_t next_row;
  __shared__ uint32_t wm;   // watermark: # of published chain entries

  const int tid = threadIdx.x;
  const int rbeg = blockIdx.x * C;
  const int rend = min(N, rbeg + C);
  if (tid == 0) { next_row = (uint32_t)(rbeg + 192); wm = 0u; }
  __syncthreads();

  const int wave = tid >> 6;
  if (wave == 0) {
    // Producer: lanes 0-2 of wave 0 walk the split() chain; publish each
    // entry with a release watermark. Other waves consume concurrently.
    int lane = tid & 63;
    uint32_t ka = 0u, kb = (uint32_t)seedp[0];
    uint32_t x1i = (lane == 2) ? 0u : (uint32_t)(lane + 1);
    for (int t = 0; t < MAXT; ++t) {
      uint32_t o0 = 0u, o1 = 0u;
      if (lane < 3) tf2x32(ka, kb, 0u, x1i, o0, o1);
      uint32_t s1a = __shfl(o0, 0, 64), s1b = __shfl(o1, 0, 64);
      uint32_t s2a = __shfl(o0, 1, 64), s2b = __shfl(o1, 1, 64);
      if (lane == 0) chain[t] = make_uint4(s1a, s1b, s2a, s2b);
      ka = __shfl(o0, 2, 64); kb = __shfl(o1, 2, 64);
      __threadfence_block();
      if (lane == 0) *(volatile uint32_t*)&wm = (uint32_t)(t + 1);
    }
    if (lane == 0) chain[MAXT] = make_uint4(0u, 0u, 0u, 0u);  // prefetch pad
    __threadfence_block();
    if (lane == 0) *(volatile uint32_t*)&wm = (uint32_t)(MAXT + 1);
  }

  const float sgi0 = __fadd_rn(1.0f, __fmul_rn(2.0f, 1e-6f));
  const float sig0 = sqrtf(__fdiv_rn(1.0f, sgi0));

  // --- per-lane row state: current row r + pre-grabbed next row rn ---
  int r, rn;
  if (wave == 0) {
    r  = (int)atomicAdd(&next_row, 1u);   // producer wave joins late; queue
    rn = (int)atomicAdd(&next_row, 1u);   // auto-balances
  } else {
    r  = rbeg + (tid - 64);               // static first 192 rows
    rn = (int)atomicAdd(&next_row, 1u);
  }
  bool have = (r < rend);
  float Zc0 = 0, Zc1 = 0, Zc2 = 0, Zn0 = 0, Zn1 = 0, Zn2 = 0;
  if (have)      { Zc0 = Z[r * 3 + 0];  Zc1 = Z[r * 3 + 1];  Zc2 = Z[r * 3 + 2]; }
  if (rn < rend) { Zn0 = Z[rn * 3 + 0]; Zn1 = Z[rn * 3 + 1]; Zn2 = Z[rn * 3 + 2]; }

  // wait for chain[0]; cache it (reused at every accept)
  uint32_t wml = *(volatile uint32_t*)&wm;
  while (wml < 1u) wml = *(volatile uint32_t*)&wm;
  __threadfence_block();
  const uint4 ck0 = chain[0];
  uint4 ck = ck0;
  bool chain_all = (wml >= (uint32_t)(MAXT + 1));
  int t = 0;

  while (__ballot(have)) {
    if (have) {
      // prefetch next iteration's subkeys NOW (full iteration of slack)
      if (!chain_all) {
        uint32_t need = (uint32_t)(t + 2);
        uint32_t w_ = *(volatile uint32_t*)&wm;
        while (w_ < need) w_ = *(volatile uint32_t*)&wm;
        __threadfence_block();
        chain_all = (w_ >= (uint32_t)(MAXT + 1));
      }
      uint4 ckn = chain[t + 1];

      const uint32_t base = ((uint32_t)r) * 4u;

      // 4 normal variates (key = s1 subkey, counters base..base+3).
      float nv[4];
#pragma unroll
      for (int j = 0; j < 4; ++j) {
        uint32_t o0, o1;
        tf2x32(ck.x, ck.y, 0u, base + (uint32_t)j, o0, o1);
        float u = u01_from_bits(o0 ^ o1);
        float xin = __fadd_rn(__fmul_rn(u, 2.0f), -0.99999994f);
        xin = fmaxf(-0.99999994f, xin);
        nv[j] = __fmul_rn(1.41421356237309504880f, xla_erfinvf(xin));
      }

      // uniform draw (key = s2 subkey, counter r)
      uint32_t uo0, uo1;
      tf2x32(ck.z, ck.w, 0u, (uint32_t)r, uo0, uo1);
      float uu = u01_from_bits(uo0 ^ uo1);

      // row-dependent constants (Z prefetched a full row-lifetime ago)
      float lam1 = -Zc0, lam2 = -Zc1, lam3 = -Zc2;
      float sgi1 = __fadd_rn(1.0f, __fmul_rn(2.0f, lam1));
      float sgi2 = __fadd_rn(1.0f, __fmul_rn(2.0f, lam2));
      float sgi3 = __fadd_rn(1.0f, __fmul_rn(2.0f, lam3));
      float sig1 = sqrtf(__fdiv_rn(1.0f, sgi1));
      float sig2 = sqrtf(__fdiv_rn(1.0f, sgi2));
      float sig3 = sqrtf(__fdiv_rn(1.0f, sgi3));

      float y0 = __fmul_rn(nv[0], sig0);
      float y1 = __fmul_rn(nv[1], sig1);
      float y2v = __fmul_rn(nv[2], sig2);
      float y3 = __fmul_rn(nv[3], sig3);

      // normalize (sequential reduce order)
      float n2 = __fmul_rn(y0, y0);
      n2 = __fadd_rn(n2, __fmul_rn(y1, y1));
      n2 = __fadd_rn(n2, __fmul_rn(y2v, y2v));
      n2 = __fadd_rn(n2, __fmul_rn(y3, y3));
      float nr = sqrtf(n2);
      y0 = __fdiv_rn(y0, nr); y1 = __fdiv_rn(y1, nr);
      y2v = __fdiv_rn(y2v, nr); y3 = __fdiv_rn(y3, nr);

      float s0q = __fmul_rn(y0, y0), s1q = __fmul_rn(y1, y1);
      float s2q = __fmul_rn(y2v, y2v), s3q = __fmul_rn(y3, y3);

      float s1 = __fmul_rn(s0q, 1e-6f);
      s1 = __fadd_rn(s1, __fmul_rn(s1q, lam1));
      s1 = __fadd_rn(s1, __fmul_rn(s2q, lam2));
      s1 = __fadd_rn(s1, __fmul_rn(s3q, lam3));

      float s2 = __fmul_rn(s0q, sgi0);
      s2 = __fadd_rn(s2, __fmul_rn(s1q, sgi1));
      s2 = __fadd_rn(s2, __fmul_rn(s2q, sgi2));
      s2 = __fadd_rn(s2, __fmul_rn(s3q, sgi3));

      float lr = __fsub_rn(-s1, 2.7725887298583984f);  // 2*f32(ln 4)
      lr = __fadd_rn(lr, 1.5f);
      lr = __fadd_rn(lr, __fmul_rn(2.0f, xla_logf_pos(s2)));

      float lu = (uu > 0.0f) ? xla_logf_pos(uu) : -__builtin_inff();

      ++t;
      if ((lu < lr) || (t >= MAXT)) {
        // lean accept path: store y; E^T deferred to pass 2
        *reinterpret_cast<float4*>(out + (size_t)r * 4) =
            make_float4(y0, y1, y2v, y3);
        r = rn; Zc0 = Zn0; Zc1 = Zn1; Zc2 = Zn2;
        t = 0;
        ck = ck0;
        have = (r < rend);
        rn = (int)atomicAdd(&next_row, 1u);   // pre-grab: ~4.5 iters of slack
        if (rn < rend) {
          Zn0 = Z[rn * 3 + 0]; Zn1 = Z[rn * 3 + 1]; Zn2 = Z[rn * 3 + 2];
        }
      } else {
        ck = ckn;
      }
    }
  }

  // --- pass 2: apply E^T over this block's chunk (coalesced) ---
  __syncthreads();   // all y-stores visible block-wide
  for (int i = rbeg + tid; i < rend; i += NT) {
    float4 yv = *reinterpret_cast<const float4*>(out + (size_t)i * 4);
    float4 qv = *reinterpret_cast<const float4*>(q + (size_t)i * 4);
    float a = qv.x, b = qv.y, c = qv.z, d = qv.w;
    float qn2 = __fmul_rn(a, a);
    qn2 = __fadd_rn(qn2, __fmul_rn(b, b));
    qn2 = __fadd_rn(qn2, __fmul_rn(c, c));
    qn2 = __fadd_rn(qn2, __fmul_rn(d, d));
    float qnr = sqrtf(qn2);
    a = __fdiv_rn(a, qnr); b = __fdiv_rn(b, qnr);
    c = __fdiv_rn(c, qnr); d = __fdiv_rn(d, qnr);
    float y0 = yv.x, y1 = yv.y, y2v = yv.z, y3 = yv.w;
    float o0v = __fadd_rn(__fadd_rn(__fadd_rn(__fmul_rn(a, y0), __fmul_rn(b, y1)),
                                    __fmul_rn(c, y2v)), __fmul_rn(d, y3));
    float o1v = __fadd_rn(__fadd_rn(__fadd_rn(__fmul_rn(-b, y0), __fmul_rn(a, y1)),
                                    __fmul_rn(-d, y2v)), __fmul_rn(c, y3));
    float o2v = __fadd_rn(__fadd_rn(__fadd_rn(__fmul_rn(-c, y0), __fmul_rn(d, y1)),
                                    __fmul_rn(a, y2v)), __fmul_rn(-b, y3));
    float o3v = __fadd_rn(__fadd_rn(__fadd_rn(__fmul_rn(d, y0), __fmul_rn(c, y1)),
                                    __fmul_rn(-b, y2v)), __fmul_rn(-a, y3));
    *reinterpret_cast<float4*>(out + (size_t)i * 4) =
        make_float4(o0v, o1v, o2v, o3v);
  }
}

extern "C" void kernel_launch(void* const* d_in, const int* in_sizes, int n_in,
                              void* d_out, int out_size, void* d_ws, size_t ws_size,
                              hipStream_t stream) {
  const float* q = (const float*)d_in[0];
  const float* Z = (const float*)d_in[1];
  const int* seed = (const int*)d_in[2];
  float* out = (float*)d_out;
  int N = in_sizes[0] / 4;

  int C = (N + GRID - 1) / GRID;  // rows per block (contiguous chunk)
  campose_kernel<<<GRID, NT, 0, stream>>>(q, Z, out, seed, N, C);
}